// Round 3
// baseline (258.128 us; speedup 1.0000x reference)
//
#include <hip/hip_runtime.h>
#include <math.h>

#define BATCH    128
#define N_ATOMS  4096
#define NB       4095
#define NA       4094
#define NT       4093
#define MAX_LEN  (5 * NT)               // 20465
#define FSTRIDE  ((size_t)MAX_LEN * 9)  // 184185 floats per sample (ODD -> 4B-aligned sample base!)
#define TOTAL_F4 ((size_t)BATCH * FSTRIDE / 4)  // whole-array float4 count (divisible: 128*184185%4==0)
#define EPSV     1e-8f
#define PARTS    4                      // 128*4 = 512 blocks = exactly 2 blocks/CU (77 KB LDS cap)
#define THREADS  256
#define TILE_F   6916                   // 6912 logical floats + up to 3 alignment slack
#define TILE_F4  1729

__global__ __launch_bounds__(THREADS) void
local_energy_kernel(const float* __restrict__ F,
                    const float* __restrict__ bond_type,   // 15 x 2
                    const float* __restrict__ angle_type,  // 13 x 2
                    const float* __restrict__ tor_type,    // 25 x 2
                    const int*   __restrict__ multiplicity,// 25
                    const float* __restrict__ opt_pars,    // 47
                    float*       __restrict__ out)         // B x 3
{
    __shared__ float scx[N_ATOMS];
    __shared__ float scy[N_ATOMS];
    __shared__ float scz[N_ATOMS];
    __shared__ __align__(16) float tile[TILE_F];
    __shared__ float sbt[30];
    __shared__ float sat[26];
    __shared__ float stt[50];
    __shared__ float smu[25];
    __shared__ float sred[12];

    // XCD swizzle: all PARTS blocks of sample s share blockIdx%8 so redundant
    // coord-region reads hit the same per-XCD L2 (R2: FETCH 218->111 MB).
    const int b   = blockIdx.x;
    const int x   = b & 7;
    const int g   = b >> 3;            // 0..63
    const int s   = (g & 15) * 8 + x;  // sample 0..127
    const int p   = g >> 4;            // part 0..3
    const int tid = threadIdx.x;
    const size_t sbase = (size_t)s * FSTRIDE;

    if (tid < 30)                      sbt[tid]       = bond_type[tid];
    else if (tid >= 32 && tid < 58)    sat[tid - 32]  = angle_type[tid - 32];
    else if (tid >= 64 && tid < 114)   stt[tid - 64]  = tor_type[tid - 64];
    else if (tid >= 128 && tid < 153)  smu[tid - 128] = (float)multiplicity[tid - 128];

    // ---- coalesced tile loader: copies raw floats [sbase+base, +span) into
    // tile[d..d+span), d = alignment slack so float4 loads are 16B-aligned ----
    // (defined inline per use below)

    // ======== Phase 1: stage coords (col 5, rows 0..3*N_ATOMS) ========
    // 16 tiles x 6912 floats = rows 0..12288, 256 atoms per tile.
    for (int t = 0; t < 16; ++t) {
        const size_t gf  = sbase + (size_t)t * 6912;
        const size_t gf0 = gf & ~(size_t)3;
        const int d      = (int)(gf - gf0);
        const float4* __restrict__ src4 = (const float4*)(F + gf0);
        const size_t q0 = gf0 >> 2;
        for (int k = tid; k < TILE_F4; k += THREADS) {
            if (q0 + k < TOTAL_F4) ((float4*)tile)[k] = src4[k];
        }
        __syncthreads();
        // local flat for (atom-in-tile=tid, comp cc) = 27*tid + 9*cc + 5
        const int a = 256 * t + tid;
        scx[a] = tile[d + 27 * tid + 5];
        scy[a] = tile[d + 27 * tid + 14];
        scz[a] = tile[d + 27 * tid + 23];
        __syncthreads();
    }

    float e_bond = 0.0f, e_ang = 0.0f, e_tor = 0.0f;
    const int chunk = 1024;            // ceil(4095/4); also used for NA/NT chunks
    const int lo = p * chunk;

    // ======== Phase 2: bonds (col 6, 27 floats per bond row-group) ========
    {
        const int hi = (lo + chunk < NB) ? lo + chunk : NB;
        for (int it = 0; it < 4; ++it) {
            const int e0 = lo + 256 * it;
            if (e0 >= hi) break;
            const size_t gf  = sbase + (size_t)27 * e0;
            const size_t gf0 = gf & ~(size_t)3;
            const int d      = (int)(gf - gf0);
            const float4* __restrict__ src4 = (const float4*)(F + gf0);
            const size_t q0 = gf0 >> 2;
            for (int k = tid; k < TILE_F4; k += THREADS) {
                if (q0 + k < TOTAL_F4) ((float4*)tile)[k] = src4[k];
            }
            __syncthreads();
            const int e = e0 + tid;
            if (e < hi) {
                const int base = d + 27 * tid;
                int a0 = (int)tile[base + 6];
                int a1 = (int)tile[base + 15];
                int bt = (int)tile[base + 24];
                float dx = scx[a0] - scx[a1];
                float dy = scy[a0] - scy[a1];
                float dz = scz[a0] - scz[a1];
                float r  = sqrtf(dx*dx + dy*dy + dz*dz + EPSV);
                float t0 = r - sbt[bt * 2 + 1];
                e_bond += sbt[bt * 2 + 0] * t0 * t0;
            }
            __syncthreads();
        }
    }

    // ======== Phase 3: angles (col 7, 36 floats per angle row-group) ========
    {
        const int hi = (lo + chunk < NA) ? lo + chunk : NA;
        for (int it = 0; it < 6; ++it) {
            const int e0 = lo + 192 * it;
            if (e0 >= hi) break;
            const size_t gf  = sbase + (size_t)36 * e0;
            const size_t gf0 = gf & ~(size_t)3;
            const int d      = (int)(gf - gf0);
            const float4* __restrict__ src4 = (const float4*)(F + gf0);
            const size_t q0 = gf0 >> 2;
            for (int k = tid; k < TILE_F4; k += THREADS) {
                if (q0 + k < TOTAL_F4) ((float4*)tile)[k] = src4[k];
            }
            __syncthreads();
            const int e = e0 + tid;
            if (tid < 192 && e < hi) {
                const int base = d + 36 * tid;
                int a0 = (int)tile[base + 7];
                int a1 = (int)tile[base + 16];
                int a2 = (int)tile[base + 25];
                int at = (int)tile[base + 34];
                float v1x = scx[a0] - scx[a1];
                float v1y = scy[a0] - scy[a1];
                float v1z = scz[a0] - scz[a1];
                float v2x = scx[a2] - scx[a1];
                float v2y = scy[a2] - scy[a1];
                float v2z = scz[a2] - scz[a1];
                float d12 = v1x*v2x + v1y*v2y + v1z*v2z;
                float n1  = sqrtf(v1x*v1x + v1y*v1y + v1z*v1z + EPSV);
                float n2  = sqrtf(v2x*v2x + v2y*v2y + v2z*v2z + EPSV);
                float cosang = d12 / (n1 * n2);
                cosang = fminf(fmaxf(cosang, -1.0f + 1e-6f), 1.0f - 1e-6f);
                float theta = acosf(cosang);
                float t0 = theta - sat[at * 2 + 1];
                e_ang += sat[at * 2 + 0] * t0 * t0;
            }
            __syncthreads();
        }
    }

    // ======== Phase 4: torsions (col 8, 45 floats per torsion row-group) ========
    {
        const int hi = (lo + chunk < NT) ? lo + chunk : NT;
        for (int it = 0; it < 8; ++it) {
            const int e0 = lo + 144 * it;
            if (e0 >= hi) break;
            const size_t gf  = sbase + (size_t)45 * e0;
            const size_t gf0 = gf & ~(size_t)3;
            const int d      = (int)(gf - gf0);
            const float4* __restrict__ src4 = (const float4*)(F + gf0);
            const size_t q0 = gf0 >> 2;
            const int nf4 = (45 * 144 + d + 3) >> 2;   // 1621 or 1622
            for (int k = tid; k < nf4; k += THREADS) {
                if (q0 + k < TOTAL_F4) ((float4*)tile)[k] = src4[k];
            }
            __syncthreads();
            const int e = e0 + tid;
            if (tid < 144 && e < hi) {
                const int base = d + 45 * tid;
                int ai = (int)tile[base + 8];
                int aj = (int)tile[base + 17];
                int ak = (int)tile[base + 26];
                int al = (int)tile[base + 35];
                int tt = (int)tile[base + 44];

                float b1x = scx[aj] - scx[ai], b1y = scy[aj] - scy[ai], b1z = scz[aj] - scz[ai];
                float b2x = scx[ak] - scx[aj], b2y = scy[ak] - scy[aj], b2z = scz[ak] - scz[aj];
                float b3x = scx[al] - scx[ak], b3y = scy[al] - scy[ak], b3z = scz[al] - scz[ak];

                float n1x = b1y*b2z - b1z*b2y;
                float n1y = b1z*b2x - b1x*b2z;
                float n1z = b1x*b2y - b1y*b2x;
                float n2x = b2y*b3z - b2z*b3y;
                float n2y = b2z*b3x - b2x*b3z;
                float n2z = b2x*b3y - b2y*b3x;

                float inv = 1.0f / sqrtf(b2x*b2x + b2y*b2y + b2z*b2z + EPSV);
                float bnx = b2x * inv, bny = b2y * inv, bnz = b2z * inv;

                float m1x = n1y*bnz - n1z*bny;
                float m1y = n1z*bnx - n1x*bnz;
                float m1z = n1x*bny - n1y*bnx;

                float sy = m1x*n2x + m1y*n2y + m1z*n2z;
                float sx = n1x*n2x + n1y*n2y + n1z*n2z;
                float phi = atan2f(sy, sx);

                e_tor += stt[tt * 2 + 0] * (1.0f + cosf(smu[tt] * phi - stt[tt * 2 + 1]));
            }
            __syncthreads();
        }
    }

    // ---- reduction: wave shuffle (width 64) -> LDS -> atomicAdd ----
    for (int off = 32; off > 0; off >>= 1) {
        e_bond += __shfl_down(e_bond, off);
        e_ang  += __shfl_down(e_ang,  off);
        e_tor  += __shfl_down(e_tor,  off);
    }
    const int wave = tid >> 6;
    const int lane = tid & 63;
    if (lane == 0) {
        sred[wave * 3 + 0] = e_bond;
        sred[wave * 3 + 1] = e_ang;
        sred[wave * 3 + 2] = e_tor;
    }
    __syncthreads();
    if (tid == 0) {
        float eb = 0.0f, ea = 0.0f, et = 0.0f;
        for (int w = 0; w < THREADS / 64; ++w) {
            eb += sred[w * 3 + 0];
            ea += sred[w * 3 + 1];
            et += sred[w * 3 + 2];
        }
        atomicAdd(&out[s * 3 + 0], opt_pars[0] * eb);
        atomicAdd(&out[s * 3 + 1], opt_pars[1] * ea);
        atomicAdd(&out[s * 3 + 2], opt_pars[2] * et);
    }
}

extern "C" void kernel_launch(void* const* d_in, const int* in_sizes, int n_in,
                              void* d_out, int out_size, void* d_ws, size_t ws_size,
                              hipStream_t stream) {
    const float* F            = (const float*)d_in[0];
    // d_in[1] = lengths (constant, unused)
    const float* bond_type    = (const float*)d_in[2];
    const float* angle_type   = (const float*)d_in[3];
    const float* tor_type     = (const float*)d_in[4];
    const int*   multiplicity = (const int*)  d_in[5];
    const float* opt_pars     = (const float*)d_in[6];
    float* out = (float*)d_out;

    hipMemsetAsync(out, 0, (size_t)out_size * sizeof(float), stream);

    dim3 grid(BATCH * PARTS);
    dim3 block(THREADS);
    local_energy_kernel<<<grid, block, 0, stream>>>(
        F, bond_type, angle_type, tor_type, multiplicity, opt_pars, out);
}

// Round 4
// 176.923 us; speedup vs baseline: 1.4590x; 1.4590x over previous
//
#include <hip/hip_runtime.h>
#include <math.h>

#define BATCH    128
#define N_ATOMS  4096
#define NB       4095
#define NA       4094
#define NT       4093
#define MAX_LEN  (5 * NT)               // 20465
#define FSTRIDE  184185                 // MAX_LEN * 9 floats per sample
#define COORD_ROWS 12288                // 3*N_ATOMS
#define BOND_ROWS  12285                // 3*NB
#define ANG_ROWS   16376                // 4*NA
#define TOR_ROWS   20465                // 5*NT
#define EPSV     1e-8f
#define THREADS  256

// ---- d_ws layout ----
// coords: 3 fp32 planes [B][4096]; then ushort index records.
#define WS_CX        0
#define WS_CY        (WS_CX + BATCH * N_ATOMS)
#define WS_CZ        (WS_CY + BATCH * N_ATOMS)
#define WS_COORD_END (WS_CZ + BATCH * N_ATOMS)                    // floats
#define WS_BONDS_B   ((size_t)WS_COORD_END * 4)                   // ushort4 per bond (a0,a1,bt,pad)
#define WS_ANGLES_B  (WS_BONDS_B + (size_t)BATCH * NB * 4 * 2)    // ushort4 per angle
#define WS_TORS_B    (WS_ANGLES_B + (size_t)BATCH * NA * 4 * 2)   // 8 ushorts (16B) per torsion
#define WS_END_B     (WS_TORS_B + (size_t)BATCH * NT * 8 * 2)     // = 23,059,456 bytes

// ======================= K1: coalesced extraction =======================
__global__ __launch_bounds__(THREADS) void
extract_kernel(const float* __restrict__ F, float* __restrict__ ws)
{
    const int b     = blockIdx.x;
    const int x     = b & 7;
    const int g     = b >> 3;            // 0..255
    const int s     = (g & 15) * 8 + x;  // sample 0..127, XCD-pinned (s%8 == x)
    const int slice = g >> 4;            // 0..15
    const size_t sbase = (size_t)s * FSTRIDE;
    const size_t q_lo  = sbase >> 2;     // first float4 covering the sample
    const int qcount   = (int)(((sbase + FSTRIDE + 3) >> 2) - q_lo);  // always 46047
    const float4* __restrict__ F4 = (const float4*)F;

    float* __restrict__ cx = ws + WS_CX + (size_t)s * N_ATOMS;
    float* __restrict__ cy = ws + WS_CY + (size_t)s * N_ATOMS;
    float* __restrict__ cz = ws + WS_CZ + (size_t)s * N_ATOMS;
    unsigned short* __restrict__ bw = (unsigned short*)((char*)ws + WS_BONDS_B)  + (size_t)s * NB * 4;
    unsigned short* __restrict__ aw = (unsigned short*)((char*)ws + WS_ANGLES_B) + (size_t)s * NA * 4;
    unsigned short* __restrict__ tw = (unsigned short*)((char*)ws + WS_TORS_B)   + (size_t)s * NT * 8;

    const int k0 = slice * 2878;                       // 16*2878 = 46048 >= 46047
    const int k1 = (k0 + 2878 < qcount) ? k0 + 2878 : qcount;
    for (int k = k0 + threadIdx.x; k < k1; k += THREADS) {
        float4 v4 = F4[q_lo + k];
        const int rel0 = (int)((q_lo + (size_t)k) * 4 - sbase);   // may be -3..-1 on first f4
        float vv[4] = {v4.x, v4.y, v4.z, v4.w};
        #pragma unroll
        for (int e = 0; e < 4; ++e) {
            const int rel = rel0 + e;
            if ((unsigned)rel >= (unsigned)FSTRIDE) continue;
            const unsigned r = (unsigned)rel / 9u;
            const unsigned c = (unsigned)rel - 9u * r;
            const float v = vv[e];
            if (c == 5u) {
                if (r < COORD_ROWS) {
                    unsigned atom = r / 3u, comp = r - 3u * atom;
                    float* plane = (comp == 0u) ? cx : ((comp == 1u) ? cy : cz);
                    plane[atom] = v;
                }
            } else if (c == 6u) {
                if (r < BOND_ROWS) {
                    unsigned i = r / 3u, f = r - 3u * i;
                    bw[i * 4u + f] = (unsigned short)(int)v;
                }
            } else if (c == 7u) {
                if (r < ANG_ROWS) {
                    unsigned i = r >> 2, f = r & 3u;
                    aw[i * 4u + f] = (unsigned short)(int)v;
                }
            } else if (c == 8u) {      // rel < FSTRIDE => r < TOR_ROWS always
                unsigned i = r / 5u, f = r - 5u * i;
                tw[i * 8u + f] = (unsigned short)(int)v;
            }
        }
    }
}

// ======================= K2: energy compute =======================
#define PARTS 6     // 128*6 = 768 blocks = 3 blocks/CU (48.5 KB LDS)
__global__ __launch_bounds__(THREADS) void
energy_kernel(const float* __restrict__ ws,
              const float* __restrict__ bond_type,
              const float* __restrict__ angle_type,
              const float* __restrict__ tor_type,
              const int*   __restrict__ multiplicity,
              const float* __restrict__ opt_pars,
              float*       __restrict__ out)
{
    __shared__ float scx[N_ATOMS];
    __shared__ float scy[N_ATOMS];
    __shared__ float scz[N_ATOMS];
    __shared__ float sbt[30];
    __shared__ float sat[26];
    __shared__ float stt[50];
    __shared__ float smu[25];
    __shared__ float sred[12];

    const int b   = blockIdx.x;
    const int x   = b & 7;
    const int g   = b >> 3;            // 0..95
    const int s   = (g & 15) * 8 + x;  // sample, same XCD slot as K1 writer
    const int p   = g >> 4;            // part 0..5
    const int tid = threadIdx.x;

    if (tid < 30)                      sbt[tid]       = bond_type[tid];
    else if (tid >= 32 && tid < 58)    sat[tid - 32]  = angle_type[tid - 32];
    else if (tid >= 64 && tid < 114)   stt[tid - 64]  = tor_type[tid - 64];
    else if (tid >= 128 && tid < 153)  smu[tid - 128] = (float)multiplicity[tid - 128];

    // coalesced coord staging from compact planes (12 float4 loads/thread)
    {
        const float4* __restrict__ cx4 = (const float4*)(ws + WS_CX + (size_t)s * N_ATOMS);
        const float4* __restrict__ cy4 = (const float4*)(ws + WS_CY + (size_t)s * N_ATOMS);
        const float4* __restrict__ cz4 = (const float4*)(ws + WS_CZ + (size_t)s * N_ATOMS);
        for (int i = tid; i < N_ATOMS / 4; i += THREADS) {
            ((float4*)scx)[i] = cx4[i];
            ((float4*)scy)[i] = cy4[i];
            ((float4*)scz)[i] = cz4[i];
        }
    }
    __syncthreads();

    float e_bond = 0.0f, e_ang = 0.0f, e_tor = 0.0f;
    const int chunk = 683;             // ceil(4095/6); covers NB/NA/NT
    const int lo = p * chunk;

    // ---- bonds: one coalesced ushort4 (8B) per element ----
    {
        const ushort4* __restrict__ bp =
            (const ushort4*)((const char*)ws + WS_BONDS_B) + (size_t)s * NB;
        const int hi = (lo + chunk < NB) ? lo + chunk : NB;
        for (int i = lo + tid; i < hi; i += THREADS) {
            ushort4 u = bp[i];
            int a0 = u.x, a1 = u.y, bt = u.z;
            float dx = scx[a0] - scx[a1];
            float dy = scy[a0] - scy[a1];
            float dz = scz[a0] - scz[a1];
            float r  = sqrtf(dx*dx + dy*dy + dz*dz + EPSV);
            float t0 = r - sbt[bt * 2 + 1];
            e_bond += sbt[bt * 2 + 0] * t0 * t0;
        }
    }

    // ---- angles: one coalesced ushort4 per element ----
    {
        const ushort4* __restrict__ ap =
            (const ushort4*)((const char*)ws + WS_ANGLES_B) + (size_t)s * NA;
        const int hi = (lo + chunk < NA) ? lo + chunk : NA;
        for (int i = lo + tid; i < hi; i += THREADS) {
            ushort4 u = ap[i];
            int a0 = u.x, a1 = u.y, a2 = u.z, at = u.w;
            float v1x = scx[a0] - scx[a1];
            float v1y = scy[a0] - scy[a1];
            float v1z = scz[a0] - scz[a1];
            float v2x = scx[a2] - scx[a1];
            float v2y = scy[a2] - scy[a1];
            float v2z = scz[a2] - scz[a1];
            float d12 = v1x*v2x + v1y*v2y + v1z*v2z;
            float n1  = sqrtf(v1x*v1x + v1y*v1y + v1z*v1z + EPSV);
            float n2  = sqrtf(v2x*v2x + v2y*v2y + v2z*v2z + EPSV);
            float cosang = d12 / (n1 * n2);
            cosang = fminf(fmaxf(cosang, -1.0f + 1e-6f), 1.0f - 1e-6f);
            float theta = acosf(cosang);
            float t0 = theta - sat[at * 2 + 1];
            e_ang += sat[at * 2 + 0] * t0 * t0;
        }
    }

    // ---- torsions: one coalesced uint4 (16B) per element ----
    {
        const uint4* __restrict__ tp =
            (const uint4*)((const char*)ws + WS_TORS_B) + (size_t)s * NT;
        const int hi = (lo + chunk < NT) ? lo + chunk : NT;
        for (int i = lo + tid; i < hi; i += THREADS) {
            uint4 w = tp[i];
            int ai = w.x & 0xFFFF, aj = w.x >> 16;
            int ak = w.y & 0xFFFF, al = w.y >> 16;
            int tt = w.z & 0xFFFF;

            float b1x = scx[aj] - scx[ai], b1y = scy[aj] - scy[ai], b1z = scz[aj] - scz[ai];
            float b2x = scx[ak] - scx[aj], b2y = scy[ak] - scy[aj], b2z = scz[ak] - scz[aj];
            float b3x = scx[al] - scx[ak], b3y = scy[al] - scy[ak], b3z = scz[al] - scz[ak];

            float n1x = b1y*b2z - b1z*b2y;
            float n1y = b1z*b2x - b1x*b2z;
            float n1z = b1x*b2y - b1y*b2x;
            float n2x = b2y*b3z - b2z*b3y;
            float n2y = b2z*b3x - b2x*b3z;
            float n2z = b2x*b3y - b2y*b3x;

            float inv = 1.0f / sqrtf(b2x*b2x + b2y*b2y + b2z*b2z + EPSV);
            float bnx = b2x * inv, bny = b2y * inv, bnz = b2z * inv;

            float m1x = n1y*bnz - n1z*bny;
            float m1y = n1z*bnx - n1x*bnz;
            float m1z = n1x*bny - n1y*bnx;

            float sy = m1x*n2x + m1y*n2y + m1z*n2z;
            float sx = n1x*n2x + n1y*n2y + n1z*n2z;
            float phi = atan2f(sy, sx);

            e_tor += stt[tt * 2 + 0] * (1.0f + cosf(smu[tt] * phi - stt[tt * 2 + 1]));
        }
    }

    for (int off = 32; off > 0; off >>= 1) {
        e_bond += __shfl_down(e_bond, off);
        e_ang  += __shfl_down(e_ang,  off);
        e_tor  += __shfl_down(e_tor,  off);
    }
    const int wave = tid >> 6;
    const int lane = tid & 63;
    if (lane == 0) {
        sred[wave * 3 + 0] = e_bond;
        sred[wave * 3 + 1] = e_ang;
        sred[wave * 3 + 2] = e_tor;
    }
    __syncthreads();
    if (tid == 0) {
        float eb = 0.0f, ea = 0.0f, et = 0.0f;
        for (int w = 0; w < THREADS / 64; ++w) {
            eb += sred[w * 3 + 0];
            ea += sred[w * 3 + 1];
            et += sred[w * 3 + 2];
        }
        atomicAdd(&out[s * 3 + 0], opt_pars[0] * eb);
        atomicAdd(&out[s * 3 + 1], opt_pars[1] * ea);
        atomicAdd(&out[s * 3 + 2], opt_pars[2] * et);
    }
}

// ============ fallback (R2 single-kernel) if ws too small ============
__global__ __launch_bounds__(THREADS) void
fused_kernel(const float* __restrict__ F,
             const float* __restrict__ bond_type,
             const float* __restrict__ angle_type,
             const float* __restrict__ tor_type,
             const int*   __restrict__ multiplicity,
             const float* __restrict__ opt_pars,
             float*       __restrict__ out)
{
    __shared__ float scx[N_ATOMS];
    __shared__ float scy[N_ATOMS];
    __shared__ float scz[N_ATOMS];
    __shared__ float sbt[30], sat[26], stt[50], smu[25], sred[12];

    const int b   = blockIdx.x;
    const int x   = b & 7;
    const int g   = b >> 3;
    const int s   = (g & 15) * 8 + x;
    const int p   = g >> 4;
    const int tid = threadIdx.x;
    const float* __restrict__ Fb = F + (size_t)s * FSTRIDE;

    if (tid < 30)                      sbt[tid]       = bond_type[tid];
    else if (tid >= 32 && tid < 58)    sat[tid - 32]  = angle_type[tid - 32];
    else if (tid >= 64 && tid < 114)   stt[tid - 64]  = tor_type[tid - 64];
    else if (tid >= 128 && tid < 153)  smu[tid - 128] = (float)multiplicity[tid - 128];

    for (int a = tid; a < N_ATOMS; a += THREADS) {
        const float* cp = Fb + 27 * a;
        scx[a] = cp[5]; scy[a] = cp[14]; scz[a] = cp[23];
    }
    __syncthreads();

    float e_bond = 0.0f, e_ang = 0.0f, e_tor = 0.0f;
    const int chunk = 683;
    const int lo = p * chunk;
    {
        const int hi = (lo + chunk < NB) ? lo + chunk : NB;
        for (int i = lo + tid; i < hi; i += THREADS) {
            const float* bp = Fb + 27 * i + 6;
            int a0 = (int)bp[0], a1 = (int)bp[9], bt = (int)bp[18];
            float dx = scx[a0]-scx[a1], dy = scy[a0]-scy[a1], dz = scz[a0]-scz[a1];
            float r = sqrtf(dx*dx + dy*dy + dz*dz + EPSV);
            float t0 = r - sbt[bt*2+1];
            e_bond += sbt[bt*2+0] * t0 * t0;
        }
    }
    {
        const int hi = (lo + chunk < NA) ? lo + chunk : NA;
        for (int i = lo + tid; i < hi; i += THREADS) {
            const float* ap = Fb + 36 * i + 7;
            int a0=(int)ap[0], a1=(int)ap[9], a2=(int)ap[18], at=(int)ap[27];
            float v1x=scx[a0]-scx[a1], v1y=scy[a0]-scy[a1], v1z=scz[a0]-scz[a1];
            float v2x=scx[a2]-scx[a1], v2y=scy[a2]-scy[a1], v2z=scz[a2]-scz[a1];
            float d12=v1x*v2x+v1y*v2y+v1z*v2z;
            float n1=sqrtf(v1x*v1x+v1y*v1y+v1z*v1z+EPSV);
            float n2=sqrtf(v2x*v2x+v2y*v2y+v2z*v2z+EPSV);
            float cosang=fminf(fmaxf(d12/(n1*n2), -1.0f+1e-6f), 1.0f-1e-6f);
            float t0 = acosf(cosang) - sat[at*2+1];
            e_ang += sat[at*2+0] * t0 * t0;
        }
    }
    {
        const int hi = (lo + chunk < NT) ? lo + chunk : NT;
        for (int i = lo + tid; i < hi; i += THREADS) {
            const float* tp = Fb + 45 * i + 8;
            int ai=(int)tp[0], aj=(int)tp[9], ak=(int)tp[18], al=(int)tp[27], tt=(int)tp[36];
            float b1x=scx[aj]-scx[ai], b1y=scy[aj]-scy[ai], b1z=scz[aj]-scz[ai];
            float b2x=scx[ak]-scx[aj], b2y=scy[ak]-scy[aj], b2z=scz[ak]-scz[aj];
            float b3x=scx[al]-scx[ak], b3y=scy[al]-scy[ak], b3z=scz[al]-scz[ak];
            float n1x=b1y*b2z-b1z*b2y, n1y=b1z*b2x-b1x*b2z, n1z=b1x*b2y-b1y*b2x;
            float n2x=b2y*b3z-b2z*b3y, n2y=b2z*b3x-b2x*b3z, n2z=b2x*b3y-b2y*b3x;
            float inv=1.0f/sqrtf(b2x*b2x+b2y*b2y+b2z*b2z+EPSV);
            float bnx=b2x*inv, bny=b2y*inv, bnz=b2z*inv;
            float m1x=n1y*bnz-n1z*bny, m1y=n1z*bnx-n1x*bnz, m1z=n1x*bny-n1y*bnx;
            float phi=atan2f(m1x*n2x+m1y*n2y+m1z*n2z, n1x*n2x+n1y*n2y+n1z*n2z);
            e_tor += stt[tt*2+0] * (1.0f + cosf(smu[tt]*phi - stt[tt*2+1]));
        }
    }
    for (int off = 32; off > 0; off >>= 1) {
        e_bond += __shfl_down(e_bond, off);
        e_ang  += __shfl_down(e_ang,  off);
        e_tor  += __shfl_down(e_tor,  off);
    }
    const int wave = tid >> 6, lane = tid & 63;
    if (lane == 0) { sred[wave*3+0]=e_bond; sred[wave*3+1]=e_ang; sred[wave*3+2]=e_tor; }
    __syncthreads();
    if (tid == 0) {
        float eb=0, ea=0, et=0;
        for (int w = 0; w < THREADS/64; ++w) { eb+=sred[w*3]; ea+=sred[w*3+1]; et+=sred[w*3+2]; }
        atomicAdd(&out[s*3+0], opt_pars[0]*eb);
        atomicAdd(&out[s*3+1], opt_pars[1]*ea);
        atomicAdd(&out[s*3+2], opt_pars[2]*et);
    }
}

extern "C" void kernel_launch(void* const* d_in, const int* in_sizes, int n_in,
                              void* d_out, int out_size, void* d_ws, size_t ws_size,
                              hipStream_t stream) {
    const float* F            = (const float*)d_in[0];
    const float* bond_type    = (const float*)d_in[2];
    const float* angle_type   = (const float*)d_in[3];
    const float* tor_type     = (const float*)d_in[4];
    const int*   multiplicity = (const int*)  d_in[5];
    const float* opt_pars     = (const float*)d_in[6];
    float* out = (float*)d_out;

    hipMemsetAsync(out, 0, (size_t)out_size * sizeof(float), stream);

    if (ws_size >= WS_END_B) {
        float* ws = (float*)d_ws;
        extract_kernel<<<dim3(BATCH * 16), dim3(THREADS), 0, stream>>>(F, ws);
        energy_kernel<<<dim3(BATCH * PARTS), dim3(THREADS), 0, stream>>>(
            ws, bond_type, angle_type, tor_type, multiplicity, opt_pars, out);
    } else {
        fused_kernel<<<dim3(BATCH * PARTS), dim3(THREADS), 0, stream>>>(
            F, bond_type, angle_type, tor_type, multiplicity, opt_pars, out);
    }
}

// Round 6
// 158.337 us; speedup vs baseline: 1.6302x; 1.1174x over previous
//
#include <hip/hip_runtime.h>
#include <math.h>

#define BATCH      128
#define N_ATOMS    4096
#define NB         4095
#define NA         4094
#define NT         4093
#define FSTRIDE    184185              // floats per sample (odd!)
#define COORD_SPAN 110592              // 9 * 3*N_ATOMS floats (coords live in rows < 12288)
#define TOTAL_F4   5893920u            // 128*184185/4 (exact)
#define EPSV       1e-8f
#define THREADS    1024
#define WAVES      16
#define TILE_F     1080                // 120 rows = 40 bonds / 30 angles / 24 torsions / 40 atoms
#define NTILES     171                 // ceil(184185/1080)
#define CTILES     103                 // ceil(110592/1080)
#define SCR_F4     272                 // per-wave scratch: up to 271 f4 (1080 + 3 align) + pad

// Compiler-level memory fence, zero hardware cost. REQUIRED around the
// wave-private LDS scratch round-trip: the store->read dependency is
// cross-lane, invisible to per-thread alias analysis (R5 failed exactly
// here: LLVM reordered ds_reads across the ds_writes). The DS pipe itself
// executes a wave's LDS ops in issue order, so a compile fence suffices —
// no s_barrier / __syncthreads needed.
#define WAVE_LDS_FENCE()  do { asm volatile("" ::: "memory"); \
                               __builtin_amdgcn_wave_barrier(); } while (0)

__global__ __launch_bounds__(THREADS, 1) void
local_energy_fused(const float* __restrict__ F,
                   const float* __restrict__ bond_type,   // 15 x 2
                   const float* __restrict__ angle_type,  // 13 x 2
                   const float* __restrict__ tor_type,    // 25 x 2
                   const int*   __restrict__ multiplicity,// 25
                   const float* __restrict__ opt_pars,    // 47
                   float*       __restrict__ out)         // B x 3
{
    __shared__ float scx[N_ATOMS];
    __shared__ float scy[N_ATOMS];
    __shared__ float scz[N_ATOMS];
    __shared__ __align__(16) float4 scr[WAVES][SCR_F4];   // 68 KB
    __shared__ float sbt[30], sat[26], stt[50], smu[25];
    __shared__ float sred[WAVES * 3];

    const int b   = blockIdx.x;
    const int x   = b & 7;             // XCD slot
    const int g   = b >> 3;            // 0..31
    const int s   = (g & 15) * 8 + x;  // sample 0..127, XCD-pinned
    const int p   = g >> 4;            // part 0..1
    const int tid = threadIdx.x;
    const int w   = tid >> 6;          // wave 0..15
    const int l   = tid & 63;          // lane
    const size_t sbase = (size_t)s * FSTRIDE;
    const int d = (int)(sbase & 3);    // sample alignment slack (tile step 1080 % 4 == 0)
    const float4* __restrict__ F4 = (const float4*)F;

    if (tid < 30)                      sbt[tid]       = bond_type[tid];
    else if (tid >= 32 && tid < 58)    sat[tid - 32]  = angle_type[tid - 32];
    else if (tid >= 64 && tid < 114)   stt[tid - 64]  = tor_type[tid - 64];
    else if (tid >= 128 && tid < 153)  smu[tid - 128] = (float)multiplicity[tid - 128];

    float* const swf = (float*)scr[w];

    // ---------------- Phase 1: stage coords into LDS planes ----------------
    {
        float4 cur[5];
        int t = w;
        {
            const size_t q0 = (sbase + (size_t)t * TILE_F) >> 2;
            const int nf = (COORD_SPAN - t * TILE_F < TILE_F) ? COORD_SPAN - t * TILE_F : TILE_F;
            const int nq = (d + nf + 3) >> 2;
            #pragma unroll
            for (int i = 0; i < 5; ++i) {
                const int k = l + 64 * i;
                cur[i] = (k < nq && q0 + k < TOTAL_F4) ? F4[q0 + k]
                                                       : make_float4(0.f, 0.f, 0.f, 0.f);
            }
        }
        for (; t < CTILES; t += WAVES) {
            const int tn = t + WAVES;
            float4 nxt[5];
            #pragma unroll
            for (int i = 0; i < 5; ++i) nxt[i] = make_float4(0.f, 0.f, 0.f, 0.f);
            if (tn < CTILES) {
                const size_t q0 = (sbase + (size_t)tn * TILE_F) >> 2;
                const int nf = (COORD_SPAN - tn * TILE_F < TILE_F) ? COORD_SPAN - tn * TILE_F : TILE_F;
                const int nq = (d + nf + 3) >> 2;
                #pragma unroll
                for (int i = 0; i < 5; ++i) {
                    const int k = l + 64 * i;
                    if (k < nq && q0 + k < TOTAL_F4) nxt[i] = F4[q0 + k];
                }
            }
            #pragma unroll
            for (int i = 0; i < 4; ++i) scr[w][l + 64 * i] = cur[i];
            if (l < 15) scr[w][l + 256] = cur[4];
            WAVE_LDS_FENCE();                       // RAW: stores -> cross-lane reads

            const int na = (N_ATOMS - 40 * t < 40) ? N_ATOMS - 40 * t : 40;
            if (l < na) {
                const int base = d + 27 * l;        // atom row group: 27 floats
                const int atom = 40 * t + l;
                scx[atom] = swf[base + 5];
                scy[atom] = swf[base + 14];
                scz[atom] = swf[base + 23];
            }
            WAVE_LDS_FENCE();                       // WAR: reads -> next iter stores
            #pragma unroll
            for (int i = 0; i < 5; ++i) cur[i] = nxt[i];
        }
    }
    __syncthreads();

    // ---------------- Phase 2: stream full sample, extract + compute ----------------
    float e_bond = 0.f, e_ang = 0.f, e_tor = 0.f;
    {
        const int tlo = (p == 0) ? 0  : 86;
        const int thi = (p == 0) ? 86 : NTILES;
        float4 cur[5];
        int t = tlo + w;
        if (t < thi) {
            const size_t q0 = (sbase + (size_t)t * TILE_F) >> 2;
            const int nf = (FSTRIDE - t * TILE_F < TILE_F) ? FSTRIDE - t * TILE_F : TILE_F;
            const int nq = (d + nf + 3) >> 2;
            #pragma unroll
            for (int i = 0; i < 5; ++i) {
                const int k = l + 64 * i;
                cur[i] = (k < nq && q0 + k < TOTAL_F4) ? F4[q0 + k]
                                                       : make_float4(0.f, 0.f, 0.f, 0.f);
            }
        }
        for (; t < thi; t += WAVES) {
            const int tn = t + WAVES;
            float4 nxt[5];
            #pragma unroll
            for (int i = 0; i < 5; ++i) nxt[i] = make_float4(0.f, 0.f, 0.f, 0.f);
            if (tn < thi) {
                const size_t q0 = (sbase + (size_t)tn * TILE_F) >> 2;
                const int nf = (FSTRIDE - tn * TILE_F < TILE_F) ? FSTRIDE - tn * TILE_F : TILE_F;
                const int nq = (d + nf + 3) >> 2;
                #pragma unroll
                for (int i = 0; i < 5; ++i) {
                    const int k = l + 64 * i;
                    if (k < nq && q0 + k < TOTAL_F4) nxt[i] = F4[q0 + k];
                }
            }
            #pragma unroll
            for (int i = 0; i < 4; ++i) scr[w][l + 64 * i] = cur[i];
            if (l < 15) scr[w][l + 256] = cur[4];
            WAVE_LDS_FENCE();                       // RAW: stores -> cross-lane reads

            // ---- bonds: tile holds bonds 40t..40t+39, fields at 27i+{6,15,24} ----
            int nb = NB - 40 * t; nb = (nb > 40) ? 40 : nb;
            if (l < nb) {
                const int base = d + 27 * l;
                const int a0 = (int)swf[base + 6];
                const int a1 = (int)swf[base + 15];
                const int bt = (int)swf[base + 24];
                const float dx = scx[a0] - scx[a1];
                const float dy = scy[a0] - scy[a1];
                const float dz = scz[a0] - scz[a1];
                const float r  = sqrtf(dx*dx + dy*dy + dz*dz + EPSV);
                const float t0 = r - sbt[bt * 2 + 1];
                e_bond += sbt[bt * 2 + 0] * t0 * t0;
            }

            // ---- angles: 30t..30t+29, fields at 36i+{7,16,25,34} ----
            int na = NA - 30 * t; na = (na > 30) ? 30 : na;
            if (l < na) {
                const int base = d + 36 * l;
                const int a0 = (int)swf[base + 7];
                const int a1 = (int)swf[base + 16];
                const int a2 = (int)swf[base + 25];
                const int at = (int)swf[base + 34];
                const float v1x = scx[a0] - scx[a1];
                const float v1y = scy[a0] - scy[a1];
                const float v1z = scz[a0] - scz[a1];
                const float v2x = scx[a2] - scx[a1];
                const float v2y = scy[a2] - scy[a1];
                const float v2z = scz[a2] - scz[a1];
                const float d12 = v1x*v2x + v1y*v2y + v1z*v2z;
                const float n1  = sqrtf(v1x*v1x + v1y*v1y + v1z*v1z + EPSV);
                const float n2  = sqrtf(v2x*v2x + v2y*v2y + v2z*v2z + EPSV);
                float cosang = d12 / (n1 * n2);
                cosang = fminf(fmaxf(cosang, -1.0f + 1e-6f), 1.0f - 1e-6f);
                const float t0 = acosf(cosang) - sat[at * 2 + 1];
                e_ang += sat[at * 2 + 0] * t0 * t0;
            }

            // ---- torsions: 24t..24t+23, fields at 45i+{8,17,26,35,44} ----
            int ntr = NT - 24 * t; ntr = (ntr > 24) ? 24 : ntr;
            if (l < ntr) {
                const int base = d + 45 * l;
                const int ai = (int)swf[base + 8];
                const int aj = (int)swf[base + 17];
                const int ak = (int)swf[base + 26];
                const int al = (int)swf[base + 35];
                const int tt = (int)swf[base + 44];

                const float b1x = scx[aj] - scx[ai], b1y = scy[aj] - scy[ai], b1z = scz[aj] - scz[ai];
                const float b2x = scx[ak] - scx[aj], b2y = scy[ak] - scy[aj], b2z = scz[ak] - scz[aj];
                const float b3x = scx[al] - scx[ak], b3y = scy[al] - scy[ak], b3z = scz[al] - scz[ak];

                const float n1x = b1y*b2z - b1z*b2y;
                const float n1y = b1z*b2x - b1x*b2z;
                const float n1z = b1x*b2y - b1y*b2x;
                const float n2x = b2y*b3z - b2z*b3y;
                const float n2y = b2z*b3x - b2x*b3z;
                const float n2z = b2x*b3y - b2y*b3x;

                const float inv = 1.0f / sqrtf(b2x*b2x + b2y*b2y + b2z*b2z + EPSV);
                const float bnx = b2x * inv, bny = b2y * inv, bnz = b2z * inv;

                const float m1x = n1y*bnz - n1z*bny;
                const float m1y = n1z*bnx - n1x*bnz;
                const float m1z = n1x*bny - n1y*bnx;

                const float sy = m1x*n2x + m1y*n2y + m1z*n2z;
                const float sx = n1x*n2x + n1y*n2y + n1z*n2z;
                const float phi = atan2f(sy, sx);

                e_tor += stt[tt * 2 + 0] * (1.0f + cosf(smu[tt] * phi - stt[tt * 2 + 1]));
            }

            WAVE_LDS_FENCE();                       // WAR: reads -> next iter stores
            #pragma unroll
            for (int i = 0; i < 5; ++i) cur[i] = nxt[i];
        }
    }

    // ---- reduction: wave shuffle -> LDS -> atomicAdd ----
    for (int off = 32; off > 0; off >>= 1) {
        e_bond += __shfl_down(e_bond, off);
        e_ang  += __shfl_down(e_ang,  off);
        e_tor  += __shfl_down(e_tor,  off);
    }
    if (l == 0) {
        sred[w * 3 + 0] = e_bond;
        sred[w * 3 + 1] = e_ang;
        sred[w * 3 + 2] = e_tor;
    }
    __syncthreads();
    if (tid == 0) {
        float eb = 0.f, ea = 0.f, et = 0.f;
        for (int i = 0; i < WAVES; ++i) {
            eb += sred[i * 3 + 0];
            ea += sred[i * 3 + 1];
            et += sred[i * 3 + 2];
        }
        atomicAdd(&out[s * 3 + 0], opt_pars[0] * eb);
        atomicAdd(&out[s * 3 + 1], opt_pars[1] * ea);
        atomicAdd(&out[s * 3 + 2], opt_pars[2] * et);
    }
}

extern "C" void kernel_launch(void* const* d_in, const int* in_sizes, int n_in,
                              void* d_out, int out_size, void* d_ws, size_t ws_size,
                              hipStream_t stream) {
    const float* F            = (const float*)d_in[0];
    // d_in[1] = lengths (constant, unused)
    const float* bond_type    = (const float*)d_in[2];
    const float* angle_type   = (const float*)d_in[3];
    const float* tor_type     = (const float*)d_in[4];
    const int*   multiplicity = (const int*)  d_in[5];
    const float* opt_pars     = (const float*)d_in[6];
    float* out = (float*)d_out;

    hipMemsetAsync(out, 0, (size_t)out_size * sizeof(float), stream);

    local_energy_fused<<<dim3(BATCH * 2), dim3(THREADS), 0, stream>>>(
        F, bond_type, angle_type, tor_type, multiplicity, opt_pars, out);
}